// Round 2
// baseline (608.465 us; speedup 1.0000x reference)
//
#include <hip/hip_runtime.h>
#include <math.h>

typedef unsigned short u16;
typedef short bf16x8 __attribute__((ext_vector_type(8)));
typedef float f32x4 __attribute__((ext_vector_type(4)));

#define DEV static __device__ __forceinline__

DEV float bf2f(u16 u) {
  union { unsigned int i; float f; } v; v.i = ((unsigned int)u) << 16; return v.f;
}
DEV u16 f2bf(float f) {
  union { float f; unsigned int i; } v; v.f = f;
  unsigned int x = v.i;
  return (u16)((x + 0x7FFFu + ((x >> 16) & 1u)) >> 16);  // RNE
}

DEV void gload16(const void* gsrc, void* ldst) {
  __builtin_amdgcn_global_load_lds(
      (__attribute__((address_space(1))) void*)gsrc,
      (__attribute__((address_space(3))) void*)ldst, 16, 0, 0);
}

DEV f32x4 mfma16(bf16x8 a, bf16x8 b, f32x4 c) {
  return __builtin_amdgcn_mfma_f32_16x16x32_bf16(a, b, c, 0, 0, 0);
}

// ---------------------------------------------------------------------------
// NT GEMM: C[M][N] = A[M][K] * Bt[N][K]^T + bias(f32), optional GELU/residual.
// A, Bt are bf16 (u16). 128x128 tile, BK=64, 4 waves of 64x64, 16x16x32 MFMA.
// LDS XOR-swizzle via pre-swizzled global source (linear LDS dest, rule #21).
// EPI: 0 = bias, 1 = bias+GELU, 2 = bias+residual(f32)
// WF32: 1 -> C is float*, else C is bf16 (u16*)
// ---------------------------------------------------------------------------
template <int EPI, int WF32>
__global__ __launch_bounds__(256)
void gemm_nt(const u16* __restrict__ A, const u16* __restrict__ Bt,
             const float* __restrict__ bias, const float* __restrict__ res,
             void* __restrict__ Cv, int M, int N, int K) {
  __shared__ __align__(16) u16 Asm[128 * 64];
  __shared__ __align__(16) u16 Bsm[128 * 64];
  const int ntn = N >> 7;
  const int tm = blockIdx.x / ntn, tn = blockIdx.x % ntn;
  const int tid = threadIdx.x;
  const int wave = tid >> 6, lane = tid & 63;
  const int wm = wave >> 1, wn = wave & 1;
  const int lg = lane >> 4, lr = lane & 15;

  f32x4 acc[4][4];
#pragma unroll
  for (int i = 0; i < 4; ++i)
#pragma unroll
    for (int j = 0; j < 4; ++j)
#pragma unroll
      for (int r = 0; r < 4; ++r) acc[i][j][r] = 0.f;

  const char* Ab = (const char*)(A + (size_t)tm * 128 * K);
  const char* Bb = (const char*)(Bt + (size_t)tn * 128 * K);
  char* As = (char*)Asm;
  char* Bs = (char*)Bsm;
  const size_t rowbytes = (size_t)K * 2;

  for (int kb = 0; kb < K; kb += 64) {
#pragma unroll
    for (int c = 0; c < 4; ++c) {
      const int chunk = wave * 4 + c;
      const int p = chunk * 1024 + lane * 16;         // linear LDS byte pos
      const int f = p ^ (((p >> 7) & 7) << 4);        // logical tile byte (involution)
      const int row = f >> 7, colb = f & 127;
      gload16(Ab + (size_t)row * rowbytes + (size_t)kb * 2 + colb, As + chunk * 1024);
      gload16(Bb + (size_t)row * rowbytes + (size_t)kb * 2 + colb, Bs + chunk * 1024);
    }
    __syncthreads();
#pragma unroll
    for (int ks = 0; ks < 2; ++ks) {
      bf16x8 af[4], bfr[4];
#pragma unroll
      for (int fm = 0; fm < 4; ++fm) {
        const int row = wm * 64 + fm * 16 + lr;
        const int addr = ((row << 7) | (ks * 64 + lg * 16)) ^ ((row & 7) << 4);
        af[fm] = *(const bf16x8*)(As + addr);
      }
#pragma unroll
      for (int fn = 0; fn < 4; ++fn) {
        const int row = wn * 64 + fn * 16 + lr;
        const int addr = ((row << 7) | (ks * 64 + lg * 16)) ^ ((row & 7) << 4);
        bfr[fn] = *(const bf16x8*)(Bs + addr);
      }
#pragma unroll
      for (int fm = 0; fm < 4; ++fm)
#pragma unroll
        for (int fn = 0; fn < 4; ++fn)
          acc[fm][fn] = mfma16(af[fm], bfr[fn], acc[fm][fn]);
    }
    __syncthreads();
  }

  // Epilogue. D layout (verified): row=(lane>>4)*4+r, col=lane&15.
#pragma unroll
  for (int fm = 0; fm < 4; ++fm)
#pragma unroll
    for (int fn = 0; fn < 4; ++fn) {
      const int col = tn * 128 + wn * 64 + fn * 16 + lr;
      const float bc = bias[col];
#pragma unroll
      for (int r = 0; r < 4; ++r) {
        const int row = tm * 128 + wm * 64 + fm * 16 + lg * 4 + r;
        float vv = acc[fm][fn][r] + bc;
        if (EPI == 1) {
          const float u = vv;
          const float t = tanhf(0.7978845608028654f * (u + 0.044715f * u * u * u));
          vv = 0.5f * u * (1.0f + t);
        } else if (EPI == 2) {
          vv += res[(size_t)row * N + col];
        }
        if (WF32)
          ((float*)Cv)[(size_t)row * N + col] = vv;
        else
          ((u16*)Cv)[(size_t)row * N + col] = f2bf(vv);
      }
    }
}

// ---------------------------------------------------------------------------
// Flash attention: wg = (b, h, 64 q-rows); 4 waves x 16 q-rows each.
// K-tiles of 64. Scores via mfma(Q, K-as-Bt); online softmax on D-layout
// registers; int32 mask read directly (mask==0 -> -1e9, matching reference);
// P -> swizzled per-wave LDS -> A-fragments; PV via pre-transposed V
// (Vt[b][h][dk][S]) so B-fragments are 16B contiguous.
// ---------------------------------------------------------------------------
__global__ __launch_bounds__(256)
void attn_kernel(const u16* __restrict__ Q, const u16* __restrict__ Km,
                 const u16* __restrict__ Vt, const int* __restrict__ mask,
                 u16* __restrict__ O) {
  const int qb = blockIdx.x & 15;
  const int bh = blockIdx.x >> 4;
  const int b = bh >> 4, h = bh & 15;
  const int wave = threadIdx.x >> 6, lane = threadIdx.x & 63;
  const int lg = lane >> 4, lr = lane & 15;
  __shared__ __align__(16) u16 Pl[4][1024];  // per-wave 16x64 P tile (2KB)
  char* Pb = (char*)&Pl[wave][0];

  const int q0 = qb * 64 + wave * 16;
  const u16* Qp = Q + ((size_t)(b * 1024 + q0)) * 1024 + h * 64;
  bf16x8 qf[2];
#pragma unroll
  for (int ks = 0; ks < 2; ++ks)
    qf[ks] = *(const bf16x8*)(Qp + (size_t)lr * 1024 + ks * 32 + lg * 8);

  float m[4], l[4];
  f32x4 accO[4];
#pragma unroll
  for (int r = 0; r < 4; ++r) { m[r] = -3e38f; l[r] = 0.f; }
#pragma unroll
  for (int fc = 0; fc < 4; ++fc)
#pragma unroll
    for (int r = 0; r < 4; ++r) accO[fc][r] = 0.f;

  const u16* Kb0 = Km + (size_t)(b * 1024) * 1024 + h * 64;
  const u16* Vb0 = Vt + (size_t)(bh * 64) * 1024;
  const int* Mb0 = mask + ((size_t)(b * 1024 + q0)) * 1024;

  for (int kb = 0; kb < 1024; kb += 64) {
    f32x4 sc[4];
#pragma unroll
    for (int fc = 0; fc < 4; ++fc)
#pragma unroll
      for (int r = 0; r < 4; ++r) sc[fc][r] = 0.f;
#pragma unroll
    for (int ks = 0; ks < 2; ++ks) {
#pragma unroll
      for (int fc = 0; fc < 4; ++fc) {
        const bf16x8 kf = *(const bf16x8*)(Kb0 + (size_t)(kb + fc * 16 + lr) * 1024 + ks * 32 + lg * 8);
        sc[fc] = mfma16(qf[ks], kf, sc[fc]);
      }
    }
    // scale + mask (mask==0 -> -1e9, exactly as reference)
    float sv[4][4];
#pragma unroll
    for (int fc = 0; fc < 4; ++fc)
#pragma unroll
      for (int r = 0; r < 4; ++r) {
        const int mv = Mb0[(size_t)(lg * 4 + r) * 1024 + kb + fc * 16 + lr];
        sv[fc][r] = mv ? sc[fc][r] * 0.125f : -1e9f;
      }
    // row max over the 64 keys of this tile
    float tm4[4];
#pragma unroll
    for (int r = 0; r < 4; ++r)
      tm4[r] = fmaxf(fmaxf(sv[0][r], sv[1][r]), fmaxf(sv[2][r], sv[3][r]));
#pragma unroll
    for (int s = 1; s < 16; s <<= 1)
#pragma unroll
      for (int r = 0; r < 4; ++r) tm4[r] = fmaxf(tm4[r], __shfl_xor(tm4[r], s));
    float alpha[4];
#pragma unroll
    for (int r = 0; r < 4; ++r) {
      const float mn = fmaxf(m[r], tm4[r]);
      alpha[r] = __expf(m[r] - mn);
      m[r] = mn;
    }
    float rs[4] = {0.f, 0.f, 0.f, 0.f};
#pragma unroll
    for (int fc = 0; fc < 4; ++fc)
#pragma unroll
      for (int r = 0; r < 4; ++r) {
        const float p = __expf(sv[fc][r] - m[r]);
        sv[fc][r] = p;
        rs[r] += p;
      }
#pragma unroll
    for (int s = 1; s < 16; s <<= 1)
#pragma unroll
      for (int r = 0; r < 4; ++r) rs[r] += __shfl_xor(rs[r], s);
#pragma unroll
    for (int r = 0; r < 4; ++r) l[r] = l[r] * alpha[r] + rs[r];
#pragma unroll
    for (int fc = 0; fc < 4; ++fc)
#pragma unroll
      for (int r = 0; r < 4; ++r) accO[fc][r] *= alpha[r];
    // P -> LDS (bf16, XOR-swizzled rows)
#pragma unroll
    for (int fc = 0; fc < 4; ++fc)
#pragma unroll
      for (int r = 0; r < 4; ++r) {
        const int row = lg * 4 + r;
        const int ad = (row * 128 + (fc * 16 + lr) * 2) ^ ((row & 7) << 4);
        *(u16*)(Pb + ad) = f2bf(sv[fc][r]);
      }
    __syncthreads();
    // PV: A = P (rows=q, k=keys), B = Vt (cols=d, k=keys)
#pragma unroll
    for (int ks = 0; ks < 2; ++ks) {
      const int ad = ((lr << 7) | (ks * 64 + lg * 16)) ^ ((lr & 7) << 4);
      const bf16x8 pa = *(const bf16x8*)(Pb + ad);
#pragma unroll
      for (int fc = 0; fc < 4; ++fc) {
        const bf16x8 vf = *(const bf16x8*)(Vb0 + (size_t)(fc * 16 + lr) * 1024 + kb + ks * 32 + lg * 8);
        accO[fc] = mfma16(pa, vf, accO[fc]);
      }
    }
    __syncthreads();
  }
  u16* Op = O + ((size_t)(b * 1024 + q0)) * 1024 + h * 64;
#pragma unroll
  for (int fc = 0; fc < 4; ++fc)
#pragma unroll
    for (int r = 0; r < 4; ++r) {
      const float inv = 1.0f / l[r];
      Op[(size_t)(lg * 4 + r) * 1024 + fc * 16 + lr] = f2bf(accO[fc][r] * inv);
    }
}

// ---------------------------------------------------------------------------
// 64x64-tiled transpose + f32->bf16 cast: out[C][R] = bf16(in[R][C]^T)
// ---------------------------------------------------------------------------
__global__ __launch_bounds__(256)
void transpose_cast(const float* __restrict__ in, u16* __restrict__ out, int R, int C) {
  __shared__ u16 t[64][65];
  const int ctiles = C >> 6;
  const int bx = blockIdx.x % ctiles, by = blockIdx.x / ctiles;
  const int tc = threadIdx.x & 63, t4 = threadIdx.x >> 6;
#pragma unroll
  for (int i = 0; i < 16; ++i) {
    const int r = i * 4 + t4;
    t[r][tc] = f2bf(in[(size_t)(by * 64 + r) * C + bx * 64 + tc]);
  }
  __syncthreads();
#pragma unroll
  for (int i = 0; i < 16; ++i) {
    const int r = i * 4 + t4;
    out[(size_t)(bx * 64 + r) * R + by * 64 + tc] = t[tc][r];
  }
}

// V [B*S][D] (bf16) -> Vt [B][H][dk][S] (bf16)
__global__ __launch_bounds__(256)
void transpose_v_kernel(const u16* __restrict__ v, u16* __restrict__ vt) {
  const int st = blockIdx.x & 15, bh = blockIdx.x >> 4;
  __shared__ u16 t[64][65];
  const int tc = threadIdx.x & 63, t4 = threadIdx.x >> 6;
  const u16* src = v + ((size_t)((bh >> 4) * 1024 + st * 64)) * 1024 + (bh & 15) * 64;
#pragma unroll
  for (int i = 0; i < 16; ++i) {
    const int r = i * 4 + t4;           // s within tile
    t[r][tc] = src[(size_t)r * 1024 + tc];
  }
  __syncthreads();
  u16* dst = vt + (size_t)bh * 64 * 1024 + st * 64;
#pragma unroll
  for (int i = 0; i < 16; ++i) {
    const int r = i * 4 + t4;           // d index
    dst[(size_t)r * 1024 + tc] = t[tc][r];
  }
}

// Row LayerNorm over D=1024: f32 in, f32 gains, bf16 out
__global__ __launch_bounds__(256)
void ln_kernel(const float* __restrict__ x, const float* __restrict__ g,
               const float* __restrict__ bb, u16* __restrict__ y) {
  const int row = blockIdx.x, tid = threadIdx.x;
  const float4 v = ((const float4*)(x + (size_t)row * 1024))[tid];
  float s = v.x + v.y + v.z + v.w;
  float ss = v.x * v.x + v.y * v.y + v.z * v.z + v.w * v.w;
#pragma unroll
  for (int mk = 1; mk < 64; mk <<= 1) {
    s += __shfl_xor(s, mk);
    ss += __shfl_xor(ss, mk);
  }
  __shared__ float sa[4], sq[4];
  const int wave = tid >> 6, lane = tid & 63;
  if (lane == 0) { sa[wave] = s; sq[wave] = ss; }
  __syncthreads();
  s = sa[0] + sa[1] + sa[2] + sa[3];
  ss = sq[0] + sq[1] + sq[2] + sq[3];
  const float mu = s * 0.0009765625f;
  const float var = ss * 0.0009765625f - mu * mu;
  const float inv = rsqrtf(var + 1e-5f);
  const float4 gg = ((const float4*)g)[tid];
  const float4 bv = ((const float4*)bb)[tid];
  ushort4 o;
  o.x = f2bf((v.x - mu) * inv * gg.x + bv.x);
  o.y = f2bf((v.y - mu) * inv * gg.y + bv.y);
  o.z = f2bf((v.z - mu) * inv * gg.z + bv.z);
  o.w = f2bf((v.w - mu) * inv * gg.w + bv.w);
  *(ushort4*)(y + (size_t)row * 1024 + tid * 4) = o;
}

extern "C" void kernel_launch(void* const* d_in, const int* in_sizes, int n_in,
                              void* d_out, int out_size, void* d_ws, size_t ws_size,
                              hipStream_t stream) {
  (void)in_sizes; (void)n_in; (void)out_size; (void)ws_size;
  const float* x  = (const float*)d_in[0];
  const int* mask = (const int*)d_in[1];
  const float* Wq = (const float*)d_in[2];  const float* bq = (const float*)d_in[3];
  const float* Wk = (const float*)d_in[4];  const float* bk = (const float*)d_in[5];
  const float* Wv = (const float*)d_in[6];  const float* bv = (const float*)d_in[7];
  const float* Wo = (const float*)d_in[8];  const float* bo = (const float*)d_in[9];
  const float* W1 = (const float*)d_in[10]; const float* b1 = (const float*)d_in[11];
  const float* W2 = (const float*)d_in[12]; const float* b2 = (const float*)d_in[13];
  const float* g1 = (const float*)d_in[14]; const float* be1 = (const float*)d_in[15];
  const float* g2 = (const float*)d_in[16]; const float* be2 = (const float*)d_in[17];

  float* out = (float*)d_out;  // also serves as the f32 residual stream x2

  u16* ws = (u16*)d_ws;
  const size_t M1 = (size_t)1024 * 1024;
  u16* y    = ws;                //  0M..8M   LN1 out, later LN2 out
  u16* q    = ws + 8 * M1;       //  8M..16M  Q
  u16* kbuf = ws + 16 * M1;      // 16M..24M  K
  u16* vbuf = ws + 24 * M1;      // 24M..32M  V, then attention output
  u16* vt   = ws + 32 * M1;      // 32M..40M  V transposed [B][H][dk][S]
  u16* hbuf = ws + 8 * M1;       //  8M..40M  FFN mid (over q/k/v/vt, all dead)
  u16* wqt  = ws + 40 * M1;
  u16* wkt  = ws + 41 * M1;
  u16* wvt  = ws + 42 * M1;
  u16* wot  = ws + 43 * M1;
  u16* w1t  = ws + 44 * M1;      // 44M..48M  [4096][1024]
  u16* w2t  = ws + 48 * M1;      // 48M..52M  [1024][4096]  (total ws: 104 MB)

  dim3 blk(256);
  transpose_cast<<<256, blk, 0, stream>>>(Wq, wqt, 1024, 1024);
  transpose_cast<<<256, blk, 0, stream>>>(Wk, wkt, 1024, 1024);
  transpose_cast<<<256, blk, 0, stream>>>(Wv, wvt, 1024, 1024);
  transpose_cast<<<256, blk, 0, stream>>>(Wo, wot, 1024, 1024);
  transpose_cast<<<1024, blk, 0, stream>>>(W1, w1t, 1024, 4096);
  transpose_cast<<<1024, blk, 0, stream>>>(W2, w2t, 4096, 1024);
  ln_kernel<<<8192, blk, 0, stream>>>(x, g1, be1, y);
  gemm_nt<0, 0><<<512, blk, 0, stream>>>(y, wqt, bq, nullptr, q, 8192, 1024, 1024);
  gemm_nt<0, 0><<<512, blk, 0, stream>>>(y, wkt, bk, nullptr, kbuf, 8192, 1024, 1024);
  gemm_nt<0, 0><<<512, blk, 0, stream>>>(y, wvt, bv, nullptr, vbuf, 8192, 1024, 1024);
  transpose_v_kernel<<<2048, blk, 0, stream>>>(vbuf, vt);
  attn_kernel<<<2048, blk, 0, stream>>>(q, kbuf, vt, mask, vbuf);
  // x2 = x + aout@Wo + bo  -> f32, stored in d_out
  gemm_nt<2, 1><<<512, blk, 0, stream>>>(vbuf, wot, bo, x, out, 8192, 1024, 1024);
  ln_kernel<<<8192, blk, 0, stream>>>(out, g2, be2, y);
  gemm_nt<1, 0><<<2048, blk, 0, stream>>>(y, w1t, b1, nullptr, hbuf, 8192, 4096, 1024);
  // out = x2 + gelu(h)@W2 + b2 (reads res=d_out, writes d_out; same-thread RAW)
  gemm_nt<2, 1><<<512, blk, 0, stream>>>(hbuf, w2t, b2, out, out, 8192, 1024, 4096);
}